// Round 10
// baseline (62.031 us; speedup 1.0000x reference)
//
#include <hip/hip_runtime.h>
#include <cstddef>

#define SB 2
#define SS 4096
#define SH 8
#define SD 64
#define SP 64          // half-window
#define SNO 129        // W+1 offsets
#define TQ 16          // query tokens per attn block
#define WN 144         // TQ + 2*SP key window
#define NT16 (SS/TQ)   // 256 tiles per batch
#define SSTR 168       // Ss row stride (f16); cols [WN,160) zero-padded for PV
#define PRIV (TQ*SSTR + 8)   // per-head slice stride (+8 f16 => bank shift 4)

typedef _Float16 f16;
typedef __attribute__((ext_vector_type(8))) _Float16 f16x8;
typedef __attribute__((ext_vector_type(4))) float floatx4;

union f16frag { f16 h[8]; ushort4 u4[2]; f16x8 v; };

__device__ __forceinline__ float fast_tanh(float x) {
  float ax = fabsf(x);
  float e = __expf(2.0f * ax);
  float t = 1.0f - 2.0f / (e + 1.0f);
  return copysignf(t, x);
}

// read 16 f32 from global, convert, store 16 f16 to LDS
__device__ __forceinline__ void cvt16(const float* __restrict__ src, f16* __restrict__ dst) {
  float4 x0 = *(const float4*)(src);
  float4 x1 = *(const float4*)(src + 4);
  float4 x2 = *(const float4*)(src + 8);
  float4 x3 = *(const float4*)(src + 12);
  f16frag a, c;
  a.h[0]=(f16)x0.x; a.h[1]=(f16)x0.y; a.h[2]=(f16)x0.z; a.h[3]=(f16)x0.w;
  a.h[4]=(f16)x1.x; a.h[5]=(f16)x1.y; a.h[6]=(f16)x1.z; a.h[7]=(f16)x1.w;
  c.h[0]=(f16)x2.x; c.h[1]=(f16)x2.y; c.h[2]=(f16)x2.z; c.h[3]=(f16)x2.w;
  c.h[4]=(f16)x3.x; c.h[5]=(f16)x3.y; c.h[6]=(f16)x3.z; c.h[7]=(f16)x3.w;
  *(ushort4*)(dst)      = a.u4[0];
  *(ushort4*)(dst + 4)  = a.u4[1];
  *(ushort4*)(dst + 8)  = c.u4[0];
  *(ushort4*)(dst + 12) = c.u4[1];
}

// ---------------- prep: project Q,K (f16 MFMA) + convert/transpose V ----------------
__global__ __launch_bounds__(256) void prep_kernel(
    const float* __restrict__ q, const float* __restrict__ k, const float* __restrict__ v,
    const float* __restrict__ Wq, const float* __restrict__ bq,
    const float* __restrict__ Wk, const float* __restrict__ bk,
    f16* __restrict__ Qf, f16* __restrict__ Kf, f16* __restrict__ Vt)
{
  __shared__ f16 sWq[64*72], sWk[64*72], sQr[64*72], sKr[64*72], sVr[64*72];
  __shared__ float sbq[64], sbk[64];

  int t = threadIdx.x;
  int blk = blockIdx.x;
  int c = blk & 63; int bh = blk >> 6; int h = bh & 7; int b = bh >> 3;
  int s0 = c * 64;

  int dr = t >> 2, e0 = (t & 3) * 16;
  cvt16(Wq + dr*64 + e0, &sWq[dr*72 + e0]);
  cvt16(Wk + dr*64 + e0, &sWk[dr*72 + e0]);
  {
    size_t rbase = ((size_t)(b*SS + s0 + dr)) * (SH*SD) + h*SD + e0;
    cvt16(q + rbase, &sQr[dr*72 + e0]);
    cvt16(k + rbase, &sKr[dr*72 + e0]);
    cvt16(v + rbase, &sVr[dr*72 + e0]);
  }
  if (t < 64) { sbq[t] = bq[t]; sbk[t] = bk[t]; }
  __syncthreads();

  int lane = t & 63, wave = t >> 6;
  int r16 = lane & 15, g = lane >> 4;

  size_t hsbase = (size_t)(b*SH + h) * SS;

  #pragma unroll
  for (int j = 0; j < 4; ++j) {
    int tt = wave + 4*j;
    int si = tt >> 2, dj = tt & 3;
    floatx4 accq = {0.f,0.f,0.f,0.f}, acck = {0.f,0.f,0.f,0.f};
    #pragma unroll
    for (int e = 0; e < 64; e += 32) {
      f16x8 aq = *(const f16x8*)&sQr[(si*16 + r16)*72 + e + g*8];
      f16x8 ak = *(const f16x8*)&sKr[(si*16 + r16)*72 + e + g*8];
      f16x8 wq8 = *(const f16x8*)&sWq[(dj*16 + r16)*72 + e + g*8];
      f16x8 wk8 = *(const f16x8*)&sWk[(dj*16 + r16)*72 + e + g*8];
      accq = __builtin_amdgcn_mfma_f32_16x16x32_f16(aq, wq8, accq, 0, 0, 0);
      acck = __builtin_amdgcn_mfma_f32_16x16x32_f16(ak, wk8, acck, 0, 0, 0);
    }
    float biasq = sbq[dj*16 + r16];
    float biask = sbk[dj*16 + r16];
    #pragma unroll
    for (int rr = 0; rr < 4; ++rr) {
      int srow = s0 + si*16 + g*4 + rr;
      Qf[(hsbase + srow)*64 + dj*16 + r16] = (f16)(accq[rr] + biasq);
      Kf[(hsbase + srow)*64 + dj*16 + r16] = (f16)(acck[rr] + biask);
    }
  }

  // V transpose: Vt[b,h,d,s]
  {
    int d = t >> 2, p4 = t & 3, sc0 = p4 * 16;
    f16frag a, c2;
    #pragma unroll
    for (int j2 = 0; j2 < 8; ++j2) a.h[j2] = sVr[(sc0 + j2)*72 + d];
    #pragma unroll
    for (int j2 = 0; j2 < 8; ++j2) c2.h[j2] = sVr[(sc0 + 8 + j2)*72 + d];
    f16* dst = Vt + ((size_t)(b*SH + h)*64 + d)*SS + s0 + sc0;
    *(ushort4*)dst       = a.u4[0];
    *(ushort4*)(dst + 4) = a.u4[1];
    *(ushort4*)(dst + 8) = c2.u4[0];
    *(ushort4*)(dst + 12)= c2.u4[1];
  }
}

// ---------------- fused attention: one block per (b,16-tile); 16 waves ------------
// wave w: head h=w>>1, half=w&1. half0: score y-tiles 0..4; half1: 5..8.
// PV: each wave owns d-half (2 d-tiles) over the full k-window.
// 512 blocks x 1024 threads; LDS ~51.6KB -> 2 blocks/CU = 32 waves/CU (max).
// 3 barriers total. af emitted in epilogue directly from Ss slices.
__global__ __launch_bounds__(1024, 8) void attn_fused(
    const f16* __restrict__ Qf, const f16* __restrict__ Kf, const f16* __restrict__ Vt,
    const float* __restrict__ ocpe, float* __restrict__ af, float* __restrict__ outp)
{
  __shared__ f16 sPriv[SH*PRIV];        // 43,136 B  per-head Ss slices (bank-staggered)
  __shared__ float sOut[TQ*68];         // 4,352 B   row-padded cross-head accumulator
  __shared__ float sObT[SH*SNO];        // 4,128 B   [h][o]

  int t = threadIdx.x;
  int lane = t & 63, wave = t >> 6;
  int r16 = lane & 15, g = lane >> 4;
  int h = wave >> 1, half = wave & 1;

  // XCD-chunked mapping (bijective: 512 = 8*64)
  int blk = blockIdx.x;
  int G = (blk & 7) * 64 + (blk >> 3);
  int b = G >> 8, t16 = G & 255;
  int t0 = t16 * TQ, yg0 = t0 - SP;

  for (int idx = t; idx < SNO*SH; idx += 1024) {
    int o = idx >> 3, h2 = idx & 7;
    sObT[h2*SNO + o] = ocpe[idx];
  }
  for (int idx = t; idx < TQ*68; idx += 1024) sOut[idx] = 0.f;   // FIX: full zero (1088 > 1024)

  f16* priv = &sPriv[h*PRIV];
  if (half == 0) {   // zero own head's pad cols [WN,160)
    #pragma unroll
    for (int j = 0; j < 4; ++j)
      priv[r16*SSTR + WN + g*4 + j] = (f16)0.f;
  }

  __syncthreads();   // sObT + sOut + pads ready

  const float* ob = &sObT[h*SNO];
  const f16* qb = Qf + ((size_t)(b*SH + h)*SS + t0 + r16)*64;
  f16x8 qa0 = *(const f16x8*)(qb + g*8);
  f16x8 qa1 = *(const f16x8*)(qb + 32 + g*8);
  const f16* kbase = Kf + ((size_t)(b*SH + h)*SS)*64;

  // scores: half0 -> y-tiles 0..4, half1 -> 5..8
  int yBeg = half ? 5 : 0, yEnd = half ? 9 : 5;
  for (int yy = yBeg; yy < yEnd; ++yy) {
    int y = yy*16 + r16;
    int ygr = yg0 + y;
    int ygc = min(max(ygr, 0), SS-1);
    bool yok = (ygr >= 0) & (ygr < SS);
    const f16* kr = kbase + (size_t)ygc * 64;
    f16x8 kb0 = *(const f16x8*)(kr + g*8);
    f16x8 kb1 = *(const f16x8*)(kr + 32 + g*8);
    floatx4 acc = {0.f,0.f,0.f,0.f};
    acc = __builtin_amdgcn_mfma_f32_16x16x32_f16(qa0, kb0, acc, 0, 0, 0);
    acc = __builtin_amdgcn_mfma_f32_16x16x32_f16(qa1, kb1, acc, 0, 0, 0);
    #pragma unroll
    for (int rr = 0; rr < 4; ++rr) {
      int i = g*4 + rr;
      int o = y - i;
      bool ook = (o >= 0) & (o <= 2*SP);
      float a = 0.f;
      if (yok & ook) a = fast_tanh(acc[rr] + ob[o]);
      priv[i*SSTR + y] = (f16)a;
    }
  }

  __syncthreads();   // all heads' Ss complete

  // PV: wave owns d-half (2 d-tiles), full 160 k-window (pad cols zero)
  floatx4 acc2[2] = {{0.f,0.f,0.f,0.f},{0.f,0.f,0.f,0.f}};
  const f16* vb0 = Vt + ((size_t)(b*SH + h)*64 + half*32 + r16)*SS;
  #pragma unroll
  for (int ks = 0; ks < 5; ++ks) {
    int yb = ks*32 + g*8;
    int ygr = yg0 + yb;
    int ygc = min(max(ygr, 0), SS-8);
    f16x8 a0 = *(const f16x8*)&priv[r16*SSTR + yb];
    #pragma unroll
    for (int dq = 0; dq < 2; ++dq) {
      f16x8 bv = *(const f16x8*)(vb0 + (size_t)(dq*16)*SS + ygc);
      acc2[dq] = __builtin_amdgcn_mfma_f32_16x16x32_f16(a0, bv, acc2[dq], 0, 0, 0);
    }
  }

  // cross-head reduce in LDS (row-padded => ~2-way worst-case conflicts)
  #pragma unroll
  for (int dq = 0; dq < 2; ++dq)
    #pragma unroll
    for (int rr = 0; rr < 4; ++rr)
      atomicAdd(&sOut[(g*4 + rr)*68 + half*32 + dq*16 + r16], acc2[dq][rr]);

  __syncthreads();   // sOut complete; Ss slices still intact

  // out: full 64B lines
  if (t < TQ*SD) {
    int i = t >> 6, d = t & 63;
    outp[((size_t)b*SS + t0 + i)*64 + d] = sOut[i*68 + d];
  }

  // af: [i][o][h] f32, generated directly from Ss slices (af[i][o][h]=Ss_h[i][i+o]);
  // slice stride PRIV staggers banks by 4 per head -> 4 reads conflict-free
  {
    float* afb = af + ((size_t)b*SS + t0) * (size_t)(SNO*SH);
    const int NF4 = TQ*SNO*SH/4;   // 4128 float4 stores
    for (int fidx = t; fidx < NF4; fidx += 1024) {
      int hq = (fidx & 1) * 4;
      int oi = fidx >> 1;
      int i = oi / SNO;
      int o = oi - i * SNO;
      const f16* s = &sPriv[hq*PRIV + i*SSTR + i + o];
      float4 w;
      w.x = (float)s[0*PRIV];
      w.y = (float)s[1*PRIV];
      w.z = (float)s[2*PRIV];
      w.w = (float)s[3*PRIV];
      *(float4*)(afb + (size_t)fidx*4) = w;
    }
  }
}

extern "C" void kernel_launch(void* const* d_in, const int* in_sizes, int n_in,
                              void* d_out, int out_size, void* d_ws, size_t ws_size,
                              hipStream_t stream) {
  const float* q    = (const float*)d_in[0];
  const float* k    = (const float*)d_in[1];
  const float* v    = (const float*)d_in[2];
  const float* Wq   = (const float*)d_in[3];
  const float* bq   = (const float*)d_in[4];
  const float* Wk   = (const float*)d_in[5];
  const float* bk   = (const float*)d_in[6];
  const float* ocpe = (const float*)d_in[7];

  // ws: Kf (8.39MB) + Vt (8.39MB) + Qf (8.39MB) = 25.2MB (fits proven 33.7MB)
  f16* Kf = (f16*)d_ws;
  f16* Vt = Kf + (size_t)SB*SH*SS*SD;
  f16* Qf = Vt + (size_t)SB*SH*SS*SD;

  float* af = (float*)d_out;
  float* op = af + (size_t)SB*SS*SNO*SH;

  prep_kernel<<<SB*SH*64, 256, 0, stream>>>(q, k, v, Wq, bq, Wk, bk, Qf, Kf, Vt);
  attn_fused<<<SB*NT16, 1024, 0, stream>>>(Qf, Kf, Vt, ocpe, af, op);
}

// Round 12
// 61.318 us; speedup vs baseline: 1.0116x; 1.0116x over previous
//
#include <hip/hip_runtime.h>
#include <cstddef>

#define SB 2
#define SS 4096
#define SH 8
#define SD 64
#define SP 64          // half-window
#define SNO 129        // W+1 offsets
#define TQ 16          // query tokens per attn block
#define WN 144         // TQ + 2*SP key window
#define NT16 (SS/TQ)   // 256 tiles per batch
#define SSTR 168       // Ss row stride (f16); cols [WN,160) zero-padded for PV
#define PRIV (TQ*SSTR + 8)   // per-head slice stride (+8 f16 => bank shift 4)

typedef _Float16 f16;
typedef __attribute__((ext_vector_type(8))) _Float16 f16x8;
typedef __attribute__((ext_vector_type(4))) float floatx4;

union f16frag { f16 h[8]; ushort4 u4[2]; f16x8 v; };

__device__ __forceinline__ float fast_tanh(float x) {
  float ax = fabsf(x);
  float e = __expf(2.0f * ax);
  float t = 1.0f - 2.0f / (e + 1.0f);
  return copysignf(t, x);
}

// read 16 f32 from global, convert, store 16 f16 to LDS
__device__ __forceinline__ void cvt16(const float* __restrict__ src, f16* __restrict__ dst) {
  float4 x0 = *(const float4*)(src);
  float4 x1 = *(const float4*)(src + 4);
  float4 x2 = *(const float4*)(src + 8);
  float4 x3 = *(const float4*)(src + 12);
  f16frag a, c;
  a.h[0]=(f16)x0.x; a.h[1]=(f16)x0.y; a.h[2]=(f16)x0.z; a.h[3]=(f16)x0.w;
  a.h[4]=(f16)x1.x; a.h[5]=(f16)x1.y; a.h[6]=(f16)x1.z; a.h[7]=(f16)x1.w;
  c.h[0]=(f16)x2.x; c.h[1]=(f16)x2.y; c.h[2]=(f16)x2.z; c.h[3]=(f16)x2.w;
  c.h[4]=(f16)x3.x; c.h[5]=(f16)x3.y; c.h[6]=(f16)x3.z; c.h[7]=(f16)x3.w;
  *(ushort4*)(dst)      = a.u4[0];
  *(ushort4*)(dst + 4)  = a.u4[1];
  *(ushort4*)(dst + 8)  = c.u4[0];
  *(ushort4*)(dst + 12) = c.u4[1];
}

// ---------------- prep: project Q,K (f16 MFMA) + convert/transpose V ----------------
__global__ __launch_bounds__(256) void prep_kernel(
    const float* __restrict__ q, const float* __restrict__ k, const float* __restrict__ v,
    const float* __restrict__ Wq, const float* __restrict__ bq,
    const float* __restrict__ Wk, const float* __restrict__ bk,
    f16* __restrict__ Qf, f16* __restrict__ Kf, f16* __restrict__ Vt)
{
  __shared__ f16 sWq[64*72], sWk[64*72], sQr[64*72], sKr[64*72], sVr[64*72];
  __shared__ float sbq[64], sbk[64];

  int t = threadIdx.x;
  int blk = blockIdx.x;
  int c = blk & 63; int bh = blk >> 6; int h = bh & 7; int b = bh >> 3;
  int s0 = c * 64;

  int dr = t >> 2, e0 = (t & 3) * 16;
  cvt16(Wq + dr*64 + e0, &sWq[dr*72 + e0]);
  cvt16(Wk + dr*64 + e0, &sWk[dr*72 + e0]);
  {
    size_t rbase = ((size_t)(b*SS + s0 + dr)) * (SH*SD) + h*SD + e0;
    cvt16(q + rbase, &sQr[dr*72 + e0]);
    cvt16(k + rbase, &sKr[dr*72 + e0]);
    cvt16(v + rbase, &sVr[dr*72 + e0]);
  }
  if (t < 64) { sbq[t] = bq[t]; sbk[t] = bk[t]; }
  __syncthreads();

  int lane = t & 63, wave = t >> 6;
  int r16 = lane & 15, g = lane >> 4;

  size_t hsbase = (size_t)(b*SH + h) * SS;

  #pragma unroll
  for (int j = 0; j < 4; ++j) {
    int tt = wave + 4*j;
    int si = tt >> 2, dj = tt & 3;
    floatx4 accq = {0.f,0.f,0.f,0.f}, acck = {0.f,0.f,0.f,0.f};
    #pragma unroll
    for (int e = 0; e < 64; e += 32) {
      f16x8 aq = *(const f16x8*)&sQr[(si*16 + r16)*72 + e + g*8];
      f16x8 ak = *(const f16x8*)&sKr[(si*16 + r16)*72 + e + g*8];
      f16x8 wq8 = *(const f16x8*)&sWq[(dj*16 + r16)*72 + e + g*8];
      f16x8 wk8 = *(const f16x8*)&sWk[(dj*16 + r16)*72 + e + g*8];
      accq = __builtin_amdgcn_mfma_f32_16x16x32_f16(aq, wq8, accq, 0, 0, 0);
      acck = __builtin_amdgcn_mfma_f32_16x16x32_f16(ak, wk8, acck, 0, 0, 0);
    }
    float biasq = sbq[dj*16 + r16];
    float biask = sbk[dj*16 + r16];
    #pragma unroll
    for (int rr = 0; rr < 4; ++rr) {
      int srow = s0 + si*16 + g*4 + rr;
      Qf[(hsbase + srow)*64 + dj*16 + r16] = (f16)(accq[rr] + biasq);
      Kf[(hsbase + srow)*64 + dj*16 + r16] = (f16)(acck[rr] + biask);
    }
  }

  // V transpose: Vt[b,h,d,s]
  {
    int d = t >> 2, p4 = t & 3, sc0 = p4 * 16;
    f16frag a, c2;
    #pragma unroll
    for (int j2 = 0; j2 < 8; ++j2) a.h[j2] = sVr[(sc0 + j2)*72 + d];
    #pragma unroll
    for (int j2 = 0; j2 < 8; ++j2) c2.h[j2] = sVr[(sc0 + 8 + j2)*72 + d];
    f16* dst = Vt + ((size_t)(b*SH + h)*64 + d)*SS + s0 + sc0;
    *(ushort4*)dst       = a.u4[0];
    *(ushort4*)(dst + 4) = a.u4[1];
    *(ushort4*)(dst + 8) = c2.u4[0];
    *(ushort4*)(dst + 12)= c2.u4[1];
  }
}

// K-tile load (2 fragments) into named regs
#define LOADK(ra, rb, yy) {                                        \
    int y_ = (yy)*16 + r16;                                        \
    int ygr_ = yg0 + y_;                                           \
    int ygc_ = min(max(ygr_, 0), SS-1);                            \
    const f16* kr_ = kbase + (size_t)ygc_ * 64;                    \
    ra = *(const f16x8*)(kr_ + g*8);                               \
    rb = *(const f16x8*)(kr_ + 32 + g*8);                          \
  }

// consume a K-tile: 2 MFMA + bias + mask + tanh + Ss store
#define COMPK(ra, rb, yy) {                                        \
    floatx4 acc_ = {0.f,0.f,0.f,0.f};                              \
    acc_ = __builtin_amdgcn_mfma_f32_16x16x32_f16(qa0, ra, acc_, 0, 0, 0); \
    acc_ = __builtin_amdgcn_mfma_f32_16x16x32_f16(qa1, rb, acc_, 0, 0, 0); \
    int y_ = (yy)*16 + r16;                                        \
    int ygr_ = yg0 + y_;                                           \
    bool yok_ = (ygr_ >= 0) & (ygr_ < SS);                         \
    _Pragma("unroll")                                              \
    for (int rr = 0; rr < 4; ++rr) {                               \
      int i_ = g*4 + rr;                                           \
      int o_ = y_ - i_;                                            \
      bool ook_ = (o_ >= 0) & (o_ <= 2*SP);                        \
      float a_ = 0.f;                                              \
      if (yok_ & ook_) a_ = fast_tanh(acc_[rr] + ob[o_]);          \
      priv[i_*SSTR + y_] = (f16)a_;                                \
    }                                                              \
  }

// V ks-group load (4 d-tile fragments)
#define LOADV(r0, r1, r2, r3, ks) {                                \
    int yb_ = (ks)*32 + g*8;                                       \
    int ygr_ = yg0 + yb_;                                          \
    int ygc_ = min(max(ygr_, 0), SS-8);                            \
    r0 = *(const f16x8*)(vbp + ygc_);                              \
    r1 = *(const f16x8*)(vbp + (size_t)(16)*SS + ygc_);            \
    r2 = *(const f16x8*)(vbp + (size_t)(32)*SS + ygc_);            \
    r3 = *(const f16x8*)(vbp + (size_t)(48)*SS + ygc_);            \
  }

#define COMPV(r0, r1, r2, r3, ks) {                                \
    int yb_ = (ks)*32 + g*8;                                       \
    f16x8 a_ = *(const f16x8*)&priv[r16*SSTR + yb_];               \
    acc2[0] = __builtin_amdgcn_mfma_f32_16x16x32_f16(a_, r0, acc2[0], 0, 0, 0); \
    acc2[1] = __builtin_amdgcn_mfma_f32_16x16x32_f16(a_, r1, acc2[1], 0, 0, 0); \
    acc2[2] = __builtin_amdgcn_mfma_f32_16x16x32_f16(a_, r2, acc2[2], 0, 0, 0); \
    acc2[3] = __builtin_amdgcn_mfma_f32_16x16x32_f16(a_, r3, acc2[3], 0, 0, 0); \
  }

// ---------------- fused attention: one block per (b,16-tile); wave = head --------
// 512 blocks x 512 threads (8 waves). VGPR cap 128 (launch_bounds 512,4) for ILP:
// K loads batched 3-wide depth-2; V loads pipelined depth-2. No barrier between
// scores and PV (own-slice). 2 barriers total.
__global__ __launch_bounds__(512, 4) void attn_fused(
    const f16* __restrict__ Qf, const f16* __restrict__ Kf, const f16* __restrict__ Vt,
    const float* __restrict__ ocpe, float* __restrict__ af, float* __restrict__ outp)
{
  __shared__ f16 sPriv[SH*PRIV];        // 43,136 B  per-head Ss slices (bank-staggered)
  __shared__ float sOut[TQ*68];         // 4,352 B   row-padded cross-head accumulator
  __shared__ float sObT[SH*SNO];        // 4,128 B   [h][o]

  int t = threadIdx.x;
  int lane = t & 63, wave = t >> 6;
  int r16 = lane & 15, g = lane >> 4;
  int h = wave;

  // XCD-chunked mapping (bijective: 512 = 8*64)
  int blk = blockIdx.x;
  int G = (blk & 7) * 64 + (blk >> 3);
  int b = G >> 8, t16 = G & 255;
  int t0 = t16 * TQ, yg0 = t0 - SP;

  for (int idx = t; idx < SNO*SH; idx += 512) {
    int o = idx >> 3, h2 = idx & 7;
    sObT[h2*SNO + o] = ocpe[idx];
  }
  for (int idx = t; idx < TQ*68; idx += 512) sOut[idx] = 0.f;

  f16* priv = &sPriv[h*PRIV];
  // zero own head's pad cols [WN,160)
  #pragma unroll
  for (int j = 0; j < 4; ++j)
    priv[r16*SSTR + WN + g*4 + j] = (f16)0.f;

  __syncthreads();   // sObT + sOut + pads ready

  const float* ob = &sObT[h*SNO];
  const f16* qb = Qf + ((size_t)(b*SH + h)*SS + t0 + r16)*64;
  f16x8 qa0 = *(const f16x8*)(qb + g*8);
  f16x8 qa1 = *(const f16x8*)(qb + 32 + g*8);
  const f16* kbase = Kf + ((size_t)(b*SH + h)*SS)*64;

  // ---- scores: 9 y-tiles, batched 3-wide, depth-2 pipeline ----
  f16x8 k0a,k0b,k1a,k1b,k2a,k2b, k3a,k3b,k4a,k4b,k5a,k5b;
  LOADK(k0a,k0b,0); LOADK(k1a,k1b,1); LOADK(k2a,k2b,2);
  LOADK(k3a,k3b,3); LOADK(k4a,k4b,4); LOADK(k5a,k5b,5);
  COMPK(k0a,k0b,0); COMPK(k1a,k1b,1); COMPK(k2a,k2b,2);
  LOADK(k0a,k0b,6); LOADK(k1a,k1b,7); LOADK(k2a,k2b,8);
  COMPK(k3a,k3b,3); COMPK(k4a,k4b,4); COMPK(k5a,k5b,5);
  COMPK(k0a,k0b,6); COMPK(k1a,k1b,7); COMPK(k2a,k2b,8);

  // ---- PV: own slice (no barrier); V pipelined depth-2 ----
  floatx4 acc2[4] = {{0.f,0.f,0.f,0.f},{0.f,0.f,0.f,0.f},{0.f,0.f,0.f,0.f},{0.f,0.f,0.f,0.f}};
  const f16* vbp = Vt + ((size_t)(b*SH + h)*64 + r16)*SS;
  f16x8 va0,va1,va2,va3, vb0,vb1,vb2,vb3;
  LOADV(va0,va1,va2,va3,0);
  LOADV(vb0,vb1,vb2,vb3,1);
  COMPV(va0,va1,va2,va3,0); LOADV(va0,va1,va2,va3,2);
  COMPV(vb0,vb1,vb2,vb3,1); LOADV(vb0,vb1,vb2,vb3,3);
  COMPV(va0,va1,va2,va3,2); LOADV(va0,va1,va2,va3,4);
  COMPV(vb0,vb1,vb2,vb3,3);
  COMPV(va0,va1,va2,va3,4);

  // cross-head reduce in LDS
  #pragma unroll
  for (int dq = 0; dq < 4; ++dq)
    #pragma unroll
    for (int rr = 0; rr < 4; ++rr)
      atomicAdd(&sOut[(g*4 + rr)*68 + dq*16 + r16], acc2[dq][rr]);

  __syncthreads();   // sOut + all Ss slices complete

  // out: 512 threads x float2 -> all 1024 elements, full 64B lines  (FIX: was t<1024 with 512 threads)
  {
    int e2 = t * 2;
    int i = e2 >> 6, d = e2 & 63;
    float2 w2 = make_float2(sOut[i*68 + d], sOut[i*68 + d + 1]);
    *(float2*)(outp + ((size_t)b*SS + t0 + i)*64 + d) = w2;
  }

  // af: [i][o][h] f32 from Ss slices; PRIV staggers banks by 4 per head
  {
    float* afb = af + ((size_t)b*SS + t0) * (size_t)(SNO*SH);
    const int NF4 = TQ*SNO*SH/4;   // 4128 float4 stores
    for (int fidx = t; fidx < NF4; fidx += 512) {
      int hq = (fidx & 1) * 4;
      int oi = fidx >> 1;
      int i = oi / SNO;
      int o = oi - i * SNO;
      const f16* s = &sPriv[hq*PRIV + i*SSTR + i + o];
      float4 w;
      w.x = (float)s[0*PRIV];
      w.y = (float)s[1*PRIV];
      w.z = (float)s[2*PRIV];
      w.w = (float)s[3*PRIV];
      *(float4*)(afb + (size_t)fidx*4) = w;
    }
  }
}

extern "C" void kernel_launch(void* const* d_in, const int* in_sizes, int n_in,
                              void* d_out, int out_size, void* d_ws, size_t ws_size,
                              hipStream_t stream) {
  const float* q    = (const float*)d_in[0];
  const float* k    = (const float*)d_in[1];
  const float* v    = (const float*)d_in[2];
  const float* Wq   = (const float*)d_in[3];
  const float* bq   = (const float*)d_in[4];
  const float* Wk   = (const float*)d_in[5];
  const float* bk   = (const float*)d_in[6];
  const float* ocpe = (const float*)d_in[7];

  // ws: Kf (8.39MB) + Vt (8.39MB) + Qf (8.39MB) = 25.2MB (fits proven 33.7MB)
  f16* Kf = (f16*)d_ws;
  f16* Vt = Kf + (size_t)SB*SH*SS*SD;
  f16* Qf = Vt + (size_t)SB*SH*SS*SD;

  float* af = (float*)d_out;
  float* op = af + (size_t)SB*SS*SNO*SH;

  prep_kernel<<<SB*SH*64, 256, 0, stream>>>(q, k, v, Wq, bq, Wk, bk, Qf, Kf, Vt);
  attn_fused<<<SB*NT16, 512, 0, stream>>>(Qf, Kf, Vt, ocpe, af, op);
}

// Round 13
// 59.668 us; speedup vs baseline: 1.0396x; 1.0277x over previous
//
#include <hip/hip_runtime.h>
#include <cstddef>

#define SB 2
#define SS 4096
#define SH 8
#define SD 64
#define SP 64          // half-window
#define SNO 129        // W+1 offsets
#define TQ 16          // query tokens per attn block
#define WN 144         // TQ + 2*SP key window
#define NT16 (SS/TQ)   // 256 tiles per batch
#define SSTR 168       // Ss row stride (f16); cols [WN,160) zero-padded for PV
#define PRIV (TQ*SSTR + 8)   // per-head slice stride (+8 f16 => bank shift 4)

typedef _Float16 f16;
typedef __attribute__((ext_vector_type(8))) _Float16 f16x8;
typedef __attribute__((ext_vector_type(4))) float floatx4;

union f16frag { f16 h[8]; ushort4 u4[2]; f16x8 v; };

__device__ __forceinline__ float fast_tanh(float x) {
  float ax = fabsf(x);
  float e = __expf(2.0f * ax);
  float t = 1.0f - 2.0f / (e + 1.0f);
  return copysignf(t, x);
}

// read 16 f32 from global, convert, store 16 f16 to LDS
__device__ __forceinline__ void cvt16(const float* __restrict__ src, f16* __restrict__ dst) {
  float4 x0 = *(const float4*)(src);
  float4 x1 = *(const float4*)(src + 4);
  float4 x2 = *(const float4*)(src + 8);
  float4 x3 = *(const float4*)(src + 12);
  f16frag a, c;
  a.h[0]=(f16)x0.x; a.h[1]=(f16)x0.y; a.h[2]=(f16)x0.z; a.h[3]=(f16)x0.w;
  a.h[4]=(f16)x1.x; a.h[5]=(f16)x1.y; a.h[6]=(f16)x1.z; a.h[7]=(f16)x1.w;
  c.h[0]=(f16)x2.x; c.h[1]=(f16)x2.y; c.h[2]=(f16)x2.z; c.h[3]=(f16)x2.w;
  c.h[4]=(f16)x3.x; c.h[5]=(f16)x3.y; c.h[6]=(f16)x3.z; c.h[7]=(f16)x3.w;
  *(ushort4*)(dst)      = a.u4[0];
  *(ushort4*)(dst + 4)  = a.u4[1];
  *(ushort4*)(dst + 8)  = c.u4[0];
  *(ushort4*)(dst + 12) = c.u4[1];
}

// ---------------- prep: project Q,K (f16 MFMA) + convert/transpose V ----------------
__global__ __launch_bounds__(256) void prep_kernel(
    const float* __restrict__ q, const float* __restrict__ k, const float* __restrict__ v,
    const float* __restrict__ Wq, const float* __restrict__ bq,
    const float* __restrict__ Wk, const float* __restrict__ bk,
    f16* __restrict__ Qf, f16* __restrict__ Kf, f16* __restrict__ Vt)
{
  __shared__ f16 sWq[64*72], sWk[64*72], sQr[64*72], sKr[64*72], sVr[64*72];
  __shared__ float sbq[64], sbk[64];

  int t = threadIdx.x;
  int blk = blockIdx.x;
  int c = blk & 63; int bh = blk >> 6; int h = bh & 7; int b = bh >> 3;
  int s0 = c * 64;

  int dr = t >> 2, e0 = (t & 3) * 16;
  cvt16(Wq + dr*64 + e0, &sWq[dr*72 + e0]);
  cvt16(Wk + dr*64 + e0, &sWk[dr*72 + e0]);
  {
    size_t rbase = ((size_t)(b*SS + s0 + dr)) * (SH*SD) + h*SD + e0;
    cvt16(q + rbase, &sQr[dr*72 + e0]);
    cvt16(k + rbase, &sKr[dr*72 + e0]);
    cvt16(v + rbase, &sVr[dr*72 + e0]);
  }
  if (t < 64) { sbq[t] = bq[t]; sbk[t] = bk[t]; }
  __syncthreads();

  int lane = t & 63, wave = t >> 6;
  int r16 = lane & 15, g = lane >> 4;

  size_t hsbase = (size_t)(b*SH + h) * SS;

  #pragma unroll
  for (int j = 0; j < 4; ++j) {
    int tt = wave + 4*j;
    int si = tt >> 2, dj = tt & 3;
    floatx4 accq = {0.f,0.f,0.f,0.f}, acck = {0.f,0.f,0.f,0.f};
    #pragma unroll
    for (int e = 0; e < 64; e += 32) {
      f16x8 aq = *(const f16x8*)&sQr[(si*16 + r16)*72 + e + g*8];
      f16x8 ak = *(const f16x8*)&sKr[(si*16 + r16)*72 + e + g*8];
      f16x8 wq8 = *(const f16x8*)&sWq[(dj*16 + r16)*72 + e + g*8];
      f16x8 wk8 = *(const f16x8*)&sWk[(dj*16 + r16)*72 + e + g*8];
      accq = __builtin_amdgcn_mfma_f32_16x16x32_f16(aq, wq8, accq, 0, 0, 0);
      acck = __builtin_amdgcn_mfma_f32_16x16x32_f16(ak, wk8, acck, 0, 0, 0);
    }
    float biasq = sbq[dj*16 + r16];
    float biask = sbk[dj*16 + r16];
    #pragma unroll
    for (int rr = 0; rr < 4; ++rr) {
      int srow = s0 + si*16 + g*4 + rr;
      Qf[(hsbase + srow)*64 + dj*16 + r16] = (f16)(accq[rr] + biasq);
      Kf[(hsbase + srow)*64 + dj*16 + r16] = (f16)(acck[rr] + biask);
    }
  }

  // V transpose: Vt[b,h,d,s]
  {
    int d = t >> 2, p4 = t & 3, sc0 = p4 * 16;
    f16frag a, c2;
    #pragma unroll
    for (int j2 = 0; j2 < 8; ++j2) a.h[j2] = sVr[(sc0 + j2)*72 + d];
    #pragma unroll
    for (int j2 = 0; j2 < 8; ++j2) c2.h[j2] = sVr[(sc0 + 8 + j2)*72 + d];
    f16* dst = Vt + ((size_t)(b*SH + h)*64 + d)*SS + s0 + sc0;
    *(ushort4*)dst       = a.u4[0];
    *(ushort4*)(dst + 4) = a.u4[1];
    *(ushort4*)(dst + 8) = c2.u4[0];
    *(ushort4*)(dst + 12)= c2.u4[1];
  }
}

// K-tile load (2 fragments) into named regs
#define LOADK(ra, rb, yy) {                                        \
    int y_ = (yy)*16 + r16;                                        \
    int ygr_ = yg0 + y_;                                           \
    int ygc_ = min(max(ygr_, 0), SS-1);                            \
    const f16* kr_ = kbase + (size_t)ygc_ * 64;                    \
    ra = *(const f16x8*)(kr_ + g*8);                               \
    rb = *(const f16x8*)(kr_ + 32 + g*8);                          \
  }

// consume a K-tile: 2 MFMA + bias + mask + tanh + Ss store
#define COMPK(ra, rb, yy) {                                        \
    floatx4 acc_ = {0.f,0.f,0.f,0.f};                              \
    acc_ = __builtin_amdgcn_mfma_f32_16x16x32_f16(qa0, ra, acc_, 0, 0, 0); \
    acc_ = __builtin_amdgcn_mfma_f32_16x16x32_f16(qa1, rb, acc_, 0, 0, 0); \
    int y_ = (yy)*16 + r16;                                        \
    int ygr_ = yg0 + y_;                                           \
    bool yok_ = (ygr_ >= 0) & (ygr_ < SS);                         \
    _Pragma("unroll")                                              \
    for (int rr = 0; rr < 4; ++rr) {                               \
      int i_ = g*4 + rr;                                           \
      int o_ = y_ - i_;                                            \
      bool ook_ = (o_ >= 0) & (o_ <= 2*SP);                        \
      float a_ = 0.f;                                              \
      if (yok_ & ook_) a_ = fast_tanh(acc_[rr] + ob[o_]);          \
      priv[i_*SSTR + y_] = (f16)a_;                                \
    }                                                              \
  }

// V ks-group load (4 d-tile fragments)
#define LOADV(r0, r1, r2, r3, ks) {                                \
    int yb_ = (ks)*32 + g*8;                                       \
    int ygr_ = yg0 + yb_;                                          \
    int ygc_ = min(max(ygr_, 0), SS-8);                            \
    r0 = *(const f16x8*)(vbp + ygc_);                              \
    r1 = *(const f16x8*)(vbp + (size_t)(16)*SS + ygc_);            \
    r2 = *(const f16x8*)(vbp + (size_t)(32)*SS + ygc_);            \
    r3 = *(const f16x8*)(vbp + (size_t)(48)*SS + ygc_);            \
  }

#define COMPV(r0, r1, r2, r3, ks) {                                \
    int yb_ = (ks)*32 + g*8;                                       \
    f16x8 a_ = *(const f16x8*)&priv[r16*SSTR + yb_];               \
    acc2[0] = __builtin_amdgcn_mfma_f32_16x16x32_f16(a_, r0, acc2[0], 0, 0, 0); \
    acc2[1] = __builtin_amdgcn_mfma_f32_16x16x32_f16(a_, r1, acc2[1], 0, 0, 0); \
    acc2[2] = __builtin_amdgcn_mfma_f32_16x16x32_f16(a_, r2, acc2[2], 0, 0, 0); \
    acc2[3] = __builtin_amdgcn_mfma_f32_16x16x32_f16(a_, r3, acc2[3], 0, 0, 0); \
  }

#define SBAR() __builtin_amdgcn_sched_barrier(0)

// ---------------- fused attention: one block per (b,16-tile); wave = head --------
// 512 blocks x 512 threads (8 waves). Latency plan:
//  - qa + 6 K-tiles issued BEFORE __syncthreads (vmcnt(0)-at-barrier completes them
//    under the staging phase) -> scores start with data ready.
//  - remaining 3 K-tiles + all V loads issued early + pinned with sched_barrier(0)
//    so the compiler cannot sink them; latency hides under tanh/MFMA compute.
__global__ __launch_bounds__(512, 4) void attn_fused(
    const f16* __restrict__ Qf, const f16* __restrict__ Kf, const f16* __restrict__ Vt,
    const float* __restrict__ ocpe, float* __restrict__ af, float* __restrict__ outp)
{
  __shared__ f16 sPriv[SH*PRIV];        // 43,136 B  per-head Ss slices (bank-staggered)
  __shared__ float sOut[TQ*68];         // 4,352 B   row-padded cross-head accumulator
  __shared__ float sObT[SH*SNO];        // 4,128 B   [h][o]

  int t = threadIdx.x;
  int lane = t & 63, wave = t >> 6;
  int r16 = lane & 15, g = lane >> 4;
  int h = wave;

  // XCD-chunked mapping (bijective: 512 = 8*64)
  int blk = blockIdx.x;
  int G = (blk & 7) * 64 + (blk >> 3);
  int b = G >> 8, t16 = G & 255;
  int t0 = t16 * TQ, yg0 = t0 - SP;

  // ---- issue Q + first 6 K-tiles immediately (complete by barrier's vmcnt(0)) ----
  const f16* qb = Qf + ((size_t)(b*SH + h)*SS + t0 + r16)*64;
  f16x8 qa0 = *(const f16x8*)(qb + g*8);
  f16x8 qa1 = *(const f16x8*)(qb + 32 + g*8);
  const f16* kbase = Kf + ((size_t)(b*SH + h)*SS)*64;
  f16x8 k0a,k0b,k1a,k1b,k2a,k2b, k3a,k3b,k4a,k4b,k5a,k5b;
  LOADK(k0a,k0b,0); LOADK(k1a,k1b,1); LOADK(k2a,k2b,2);
  LOADK(k3a,k3b,3); LOADK(k4a,k4b,4); LOADK(k5a,k5b,5);
  SBAR();   // pin: the 14 loads above are issued before any staging below

  for (int idx = t; idx < SNO*SH; idx += 512) {
    int o = idx >> 3, h2 = idx & 7;
    sObT[h2*SNO + o] = ocpe[idx];
  }
  for (int idx = t; idx < TQ*68; idx += 512) sOut[idx] = 0.f;

  f16* priv = &sPriv[h*PRIV];
  // zero own head's pad cols [WN,160)
  #pragma unroll
  for (int j = 0; j < 4; ++j)
    priv[r16*SSTR + WN + g*4 + j] = (f16)0.f;

  __syncthreads();   // sObT + sOut + pads ready; prefetched loads complete

  const float* ob = &sObT[h*SNO];

  // ---- issue first two V ks-groups early (hide under scores compute) ----
  floatx4 acc2[4] = {{0.f,0.f,0.f,0.f},{0.f,0.f,0.f,0.f},{0.f,0.f,0.f,0.f},{0.f,0.f,0.f,0.f}};
  const f16* vbp = Vt + ((size_t)(b*SH + h)*64 + r16)*SS;
  f16x8 va0,va1,va2,va3, vb0,vb1,vb2,vb3;
  LOADV(va0,va1,va2,va3,0);
  LOADV(vb0,vb1,vb2,vb3,1);
  SBAR();   // V(0,1) issued before scores compute

  // ---- scores: tiles 0-2 compute while tiles 6-8 load ----
  COMPK(k0a,k0b,0); COMPK(k1a,k1b,1); COMPK(k2a,k2b,2);
  SBAR();
  LOADK(k0a,k0b,6); LOADK(k1a,k1b,7); LOADK(k2a,k2b,8);
  SBAR();   // K(6,7,8) issued before the remaining compute
  COMPK(k3a,k3b,3); COMPK(k4a,k4b,4); COMPK(k5a,k5b,5);
  COMPK(k0a,k0b,6); COMPK(k1a,k1b,7); COMPK(k2a,k2b,8);

  // ---- PV: own slice (no barrier); V pipelined depth-2, pinned ----
  COMPV(va0,va1,va2,va3,0); SBAR(); LOADV(va0,va1,va2,va3,2); SBAR();
  COMPV(vb0,vb1,vb2,vb3,1); SBAR(); LOADV(vb0,vb1,vb2,vb3,3); SBAR();
  COMPV(va0,va1,va2,va3,2); SBAR(); LOADV(va0,va1,va2,va3,4); SBAR();
  COMPV(vb0,vb1,vb2,vb3,3);
  COMPV(va0,va1,va2,va3,4);

  // cross-head reduce in LDS
  #pragma unroll
  for (int dq = 0; dq < 4; ++dq)
    #pragma unroll
    for (int rr = 0; rr < 4; ++rr)
      atomicAdd(&sOut[(g*4 + rr)*68 + dq*16 + r16], acc2[dq][rr]);

  __syncthreads();   // sOut + all Ss slices complete

  // out: 512 threads x float2 -> all 1024 elements, full 64B lines
  {
    int e2 = t * 2;
    int i = e2 >> 6, d = e2 & 63;
    float2 w2 = make_float2(sOut[i*68 + d], sOut[i*68 + d + 1]);
    *(float2*)(outp + ((size_t)b*SS + t0 + i)*64 + d) = w2;
  }

  // af: [i][o][h] f32 from Ss slices; PRIV staggers banks by 4 per head
  {
    float* afb = af + ((size_t)b*SS + t0) * (size_t)(SNO*SH);
    const int NF4 = TQ*SNO*SH/4;   // 4128 float4 stores
    for (int fidx = t; fidx < NF4; fidx += 512) {
      int hq = (fidx & 1) * 4;
      int oi = fidx >> 1;
      int i = oi / SNO;
      int o = oi - i * SNO;
      const f16* s = &sPriv[hq*PRIV + i*SSTR + i + o];
      float4 w;
      w.x = (float)s[0*PRIV];
      w.y = (float)s[1*PRIV];
      w.z = (float)s[2*PRIV];
      w.w = (float)s[3*PRIV];
      *(float4*)(afb + (size_t)fidx*4) = w;
    }
  }
}

extern "C" void kernel_launch(void* const* d_in, const int* in_sizes, int n_in,
                              void* d_out, int out_size, void* d_ws, size_t ws_size,
                              hipStream_t stream) {
  const float* q    = (const float*)d_in[0];
  const float* k    = (const float*)d_in[1];
  const float* v    = (const float*)d_in[2];
  const float* Wq   = (const float*)d_in[3];
  const float* bq   = (const float*)d_in[4];
  const float* Wk   = (const float*)d_in[5];
  const float* bk   = (const float*)d_in[6];
  const float* ocpe = (const float*)d_in[7];

  // ws: Kf (8.39MB) + Vt (8.39MB) + Qf (8.39MB) = 25.2MB (fits proven 33.7MB)
  f16* Kf = (f16*)d_ws;
  f16* Vt = Kf + (size_t)SB*SH*SS*SD;
  f16* Qf = Vt + (size_t)SB*SH*SS*SD;

  float* af = (float*)d_out;
  float* op = af + (size_t)SB*SS*SNO*SH;

  prep_kernel<<<SB*SH*64, 256, 0, stream>>>(q, k, v, Wq, bq, Wk, bk, Qf, Kf, Vt);
  attn_fused<<<SB*NT16, 512, 0, stream>>>(Qf, Kf, Vt, ocpe, af, op);
}

// Round 14
// 44.755 us; speedup vs baseline: 1.3860x; 1.3332x over previous
//
#include <hip/hip_runtime.h>
#include <cstddef>

#define SB 2
#define SS 4096
#define SH 8
#define SD 64
#define SP 64          // half-window
#define SNO 129        // W+1 offsets
#define TQ 16          // query tokens per attn block
#define WN 144         // TQ + 2*SP key window
#define NT16 (SS/TQ)   // 256 tiles per batch
#define SSTR 168       // Ss row stride (f16); cols [WN,160) zero-padded for PV

typedef _Float16 f16;
typedef __attribute__((ext_vector_type(8))) _Float16 f16x8;
typedef __attribute__((ext_vector_type(4))) float floatx4;

union f16frag { f16 h[8]; ushort4 u4[2]; f16x8 v; };

__device__ __forceinline__ float fast_tanh(float x) {
  float ax = fabsf(x);
  float e = __expf(2.0f * ax);
  float t = 1.0f - 2.0f / (e + 1.0f);
  return copysignf(t, x);
}

// read 16 f32 from global, convert, store 16 f16 to LDS
__device__ __forceinline__ void cvt16(const float* __restrict__ src, f16* __restrict__ dst) {
  float4 x0 = *(const float4*)(src);
  float4 x1 = *(const float4*)(src + 4);
  float4 x2 = *(const float4*)(src + 8);
  float4 x3 = *(const float4*)(src + 12);
  f16frag a, c;
  a.h[0]=(f16)x0.x; a.h[1]=(f16)x0.y; a.h[2]=(f16)x0.z; a.h[3]=(f16)x0.w;
  a.h[4]=(f16)x1.x; a.h[5]=(f16)x1.y; a.h[6]=(f16)x1.z; a.h[7]=(f16)x1.w;
  c.h[0]=(f16)x2.x; c.h[1]=(f16)x2.y; c.h[2]=(f16)x2.z; c.h[3]=(f16)x2.w;
  c.h[4]=(f16)x3.x; c.h[5]=(f16)x3.y; c.h[6]=(f16)x3.z; c.h[7]=(f16)x3.w;
  *(ushort4*)(dst)      = a.u4[0];
  *(ushort4*)(dst + 4)  = a.u4[1];
  *(ushort4*)(dst + 8)  = c.u4[0];
  *(ushort4*)(dst + 12) = c.u4[1];
}

// ---------------- prep: project Q,K (f16 MFMA) + convert/transpose V ----------------
__global__ __launch_bounds__(256) void prep_kernel(
    const float* __restrict__ q, const float* __restrict__ k, const float* __restrict__ v,
    const float* __restrict__ Wq, const float* __restrict__ bq,
    const float* __restrict__ Wk, const float* __restrict__ bk,
    f16* __restrict__ Qf, f16* __restrict__ Kf, f16* __restrict__ Vt)
{
  __shared__ f16 sWq[64*72], sWk[64*72], sQr[64*72], sKr[64*72], sVr[64*72];
  __shared__ float sbq[64], sbk[64];

  int t = threadIdx.x;
  int blk = blockIdx.x;
  int c = blk & 63; int bh = blk >> 6; int h = bh & 7; int b = bh >> 3;
  int s0 = c * 64;

  int dr = t >> 2, e0 = (t & 3) * 16;
  cvt16(Wq + dr*64 + e0, &sWq[dr*72 + e0]);
  cvt16(Wk + dr*64 + e0, &sWk[dr*72 + e0]);
  {
    size_t rbase = ((size_t)(b*SS + s0 + dr)) * (SH*SD) + h*SD + e0;
    cvt16(q + rbase, &sQr[dr*72 + e0]);
    cvt16(k + rbase, &sKr[dr*72 + e0]);
    cvt16(v + rbase, &sVr[dr*72 + e0]);
  }
  if (t < 64) { sbq[t] = bq[t]; sbk[t] = bk[t]; }
  __syncthreads();

  int lane = t & 63, wave = t >> 6;
  int r16 = lane & 15, g = lane >> 4;

  size_t hsbase = (size_t)(b*SH + h) * SS;

  #pragma unroll
  for (int j = 0; j < 4; ++j) {
    int tt = wave + 4*j;
    int si = tt >> 2, dj = tt & 3;
    floatx4 accq = {0.f,0.f,0.f,0.f}, acck = {0.f,0.f,0.f,0.f};
    #pragma unroll
    for (int e = 0; e < 64; e += 32) {
      f16x8 aq = *(const f16x8*)&sQr[(si*16 + r16)*72 + e + g*8];
      f16x8 ak = *(const f16x8*)&sKr[(si*16 + r16)*72 + e + g*8];
      f16x8 wq8 = *(const f16x8*)&sWq[(dj*16 + r16)*72 + e + g*8];
      f16x8 wk8 = *(const f16x8*)&sWk[(dj*16 + r16)*72 + e + g*8];
      accq = __builtin_amdgcn_mfma_f32_16x16x32_f16(aq, wq8, accq, 0, 0, 0);
      acck = __builtin_amdgcn_mfma_f32_16x16x32_f16(ak, wk8, acck, 0, 0, 0);
    }
    float biasq = sbq[dj*16 + r16];
    float biask = sbk[dj*16 + r16];
    #pragma unroll
    for (int rr = 0; rr < 4; ++rr) {
      int srow = s0 + si*16 + g*4 + rr;
      Qf[(hsbase + srow)*64 + dj*16 + r16] = (f16)(accq[rr] + biasq);
      Kf[(hsbase + srow)*64 + dj*16 + r16] = (f16)(acck[rr] + biask);
    }
  }

  // V transpose: Vt[b,h,d,s]
  {
    int d = t >> 2, p4 = t & 3, sc0 = p4 * 16;
    f16frag a, c2;
    #pragma unroll
    for (int j2 = 0; j2 < 8; ++j2) a.h[j2] = sVr[(sc0 + j2)*72 + d];
    #pragma unroll
    for (int j2 = 0; j2 < 8; ++j2) c2.h[j2] = sVr[(sc0 + 8 + j2)*72 + d];
    f16* dst = Vt + ((size_t)(b*SH + h)*64 + d)*SS + s0 + sc0;
    *(ushort4*)dst       = a.u4[0];
    *(ushort4*)(dst + 4) = a.u4[1];
    *(ushort4*)(dst + 8) = c2.u4[0];
    *(ushort4*)(dst + 12)= c2.u4[1];
  }
}

// ---------------- fused attention: one block per (b,16-tile); wave = head --------
// 512 blocks x 512 threads (8 waves). Each wave handles one head end-to-end using
// a wave-PRIVATE Ss slice (no barrier: same-wave ds_write->ds_read is ordered).
// Atomic-free epilogue: per-wave f32 out-dump into own slice + cross-head reduce;
// af stashed into sAF during scores, linear f16->f32 copy at the end.
// (R8 structure — measured best; R10+'s LDS-atomic + gather epilogue cost +15us.)
__global__ __launch_bounds__(512, 4) void attn_fused(
    const f16* __restrict__ Qf, const f16* __restrict__ Kf, const f16* __restrict__ Vt,
    const float* __restrict__ ocpe, float* __restrict__ af, float* __restrict__ outp)
{
  __shared__ f16 sPriv[SH][TQ*SSTR];    // 43,008 B (per-wave Ss; later f32 out-partials)
  __shared__ f16 sAF[TQ*SNO*SH];        // 33,024 B  [i][o][h]
  __shared__ float sObT[SH*SNO];        // 4,128 B   [h][o]

  int t = threadIdx.x;
  int lane = t & 63, wave = t >> 6;
  int r16 = lane & 15, g = lane >> 4;

  // XCD-chunked mapping (bijective: 512 = 8*64)
  int blk = blockIdx.x;
  int G = (blk & 7) * 64 + (blk >> 3);
  int b = G >> 8, t16 = G & 255;
  int t0 = t16 * TQ, yg0 = t0 - SP;

  for (int idx = t; idx < SNO*SH; idx += 512) {
    int o = idx >> 3, h2 = idx & 7;
    sObT[h2*SNO + o] = ocpe[idx];
  }

  int h = wave;
  f16* priv = &sPriv[wave][0];
  // zero own pad cols [WN,160)
  #pragma unroll
  for (int j = 0; j < 4; ++j)
    priv[r16*SSTR + WN + g*4 + j] = (f16)0.f;

  __syncthreads();   // sObT visible

  const float* ob = &sObT[h*SNO];
  const f16* qb = Qf + ((size_t)(b*SH + h)*SS + t0 + r16)*64;
  f16x8 qa0 = *(const f16x8*)(qb + g*8);
  f16x8 qa1 = *(const f16x8*)(qb + 32 + g*8);
  const f16* kbase = Kf + ((size_t)(b*SH + h)*SS)*64;

  // scores: 9 y-tiles cover y in [0,144)
  #pragma unroll
  for (int yy = 0; yy < 9; ++yy) {
    int y = yy*16 + r16;
    int ygr = yg0 + y;
    int ygc = min(max(ygr, 0), SS-1);
    bool yok = (ygr >= 0) & (ygr < SS);
    const f16* kr = kbase + (size_t)ygc * 64;
    f16x8 kb0 = *(const f16x8*)(kr + g*8);
    f16x8 kb1 = *(const f16x8*)(kr + 32 + g*8);
    floatx4 acc = {0.f,0.f,0.f,0.f};
    acc = __builtin_amdgcn_mfma_f32_16x16x32_f16(qa0, kb0, acc, 0, 0, 0);
    acc = __builtin_amdgcn_mfma_f32_16x16x32_f16(qa1, kb1, acc, 0, 0, 0);
    #pragma unroll
    for (int rr = 0; rr < 4; ++rr) {
      int i = g*4 + rr;
      int o = y - i;
      bool ook = (o >= 0) & (o <= 2*SP);
      float a = 0.f;
      if (yok & ook) a = fast_tanh(acc[rr] + ob[o]);
      priv[i*SSTR + y] = (f16)a;
      if (ook) sAF[((size_t)i*SNO + o)*SH + h] = (f16)a;
    }
  }

  // PV: this wave, all 4 d-tiles, k over the 160-window (pad cols are zero)
  floatx4 acc2[4] = {{0.f,0.f,0.f,0.f},{0.f,0.f,0.f,0.f},{0.f,0.f,0.f,0.f},{0.f,0.f,0.f,0.f}};
  const f16* vb0 = Vt + ((size_t)(b*SH + h)*64 + r16)*SS;
  #pragma unroll
  for (int ks = 0; ks < 5; ++ks) {
    int yb = ks*32 + g*8;
    int ygr = yg0 + yb;
    int ygc = min(max(ygr, 0), SS-8);
    f16x8 a0 = *(const f16x8*)&priv[r16*SSTR + yb];
    #pragma unroll
    for (int dq = 0; dq < 4; ++dq) {
      f16x8 bv = *(const f16x8*)(vb0 + (size_t)(dq*16)*SS + ygc);
      acc2[dq] = __builtin_amdgcn_mfma_f32_16x16x32_f16(a0, bv, acc2[dq], 0, 0, 0);
    }
  }

  // dump out-partial into OWN priv slice as f32 [i][d] (4096B <= 5376B slice)
  {
    float* po = (float*)priv;
    #pragma unroll
    for (int dq = 0; dq < 4; ++dq)
      #pragma unroll
      for (int rr = 0; rr < 4; ++rr)
        po[(g*4 + rr)*64 + dq*16 + r16] = acc2[dq][rr];
  }

  __syncthreads();   // all waves' priv out-partials + sAF complete

  // out: cross-head reduce, 512 threads x float2 -> full 64B lines
  {
    int e2 = t * 2;
    int i = e2 >> 6, d = e2 & 63;
    float sx = 0.f, sy = 0.f;
    #pragma unroll
    for (int h2 = 0; h2 < SH; ++h2) {
      const float* ph = (const float*)&sPriv[h2][0];
      sx += ph[i*64 + d];
      sy += ph[i*64 + d + 1];
    }
    *(float2*)(outp + ((size_t)b*SS + t0 + i)*64 + d) = make_float2(sx, sy);
  }

  // af: flat f16 -> f32 streaming copy (full lines)
  {
    float* afb = af + ((size_t)b*SS + t0) * (size_t)(SNO*SH);
    for (int idx = t; idx < TQ*SNO*SH/4; idx += 512) {
      const f16* s = &sAF[idx*4];
      float4 w = make_float4((float)s[0], (float)s[1], (float)s[2], (float)s[3]);
      *(float4*)(afb + idx*4) = w;
    }
  }
}

extern "C" void kernel_launch(void* const* d_in, const int* in_sizes, int n_in,
                              void* d_out, int out_size, void* d_ws, size_t ws_size,
                              hipStream_t stream) {
  const float* q    = (const float*)d_in[0];
  const float* k    = (const float*)d_in[1];
  const float* v    = (const float*)d_in[2];
  const float* Wq   = (const float*)d_in[3];
  const float* bq   = (const float*)d_in[4];
  const float* Wk   = (const float*)d_in[5];
  const float* bk   = (const float*)d_in[6];
  const float* ocpe = (const float*)d_in[7];

  // ws: Kf (8.39MB) + Vt (8.39MB) + Qf (8.39MB) = 25.2MB (fits proven 33.7MB)
  f16* Kf = (f16*)d_ws;
  f16* Vt = Kf + (size_t)SB*SH*SS*SD;
  f16* Qf = Vt + (size_t)SB*SH*SS*SD;

  float* af = (float*)d_out;
  float* op = af + (size_t)SB*SS*SNO*SH;

  prep_kernel<<<SB*SH*64, 256, 0, stream>>>(q, k, v, Wq, bq, Wk, bk, Qf, Kf, Vt);
  attn_fused<<<SB*NT16, 512, 0, stream>>>(Qf, Kf, Vt, ocpe, af, op);
}